// Round 1
// baseline (199.336 us; speedup 1.0000x reference)
//
#include <hip/hip_runtime.h>
#include <hip/hip_bf16.h>
#include <stdint.h>

#define NN 50000
#define NE 800000
#define DD 128
#define NCHUNK 3125      // NN/16
#define NB_SCAN 196      // ceil(NN/256)

// ---------- W transpose: Wt[k][j] = W[j][k] ----------
__global__ __launch_bounds__(256) void transpose_w_k(const float* __restrict__ W,
                                                     float* __restrict__ Wt) {
    int i = blockIdx.x * 256 + threadIdx.x;
    if (i < DD * DD) {
        int j = i >> 7, k = i & 127;
        Wt[k * DD + j] = W[i];
    }
}

// ---------- GEMM: h = x @ W^T, plus s = h@a_src, d = h@a_dst ----------
// wave = 16 rows; lane: cg = l&15 owns 8 cols (c0=8*cg), rg = l>>4 owns 4 rows.
__global__ __launch_bounds__(256) void gemm_h_k(const float* __restrict__ x,
                                                const float* __restrict__ Wt,
                                                const float* __restrict__ a,
                                                float* __restrict__ h,
                                                float* __restrict__ sArr,
                                                float* __restrict__ dArr) {
    __shared__ float xs[4][16 * 132];   // per-wave region, stride 132 (pad: 2-way banks only)
    const int tid = threadIdx.x;
    const int wid = tid >> 6;
    const int l   = tid & 63;
    const int chunk = blockIdx.x * 4 + wid;
    if (chunk >= NCHUNK) return;        // no block barrier used -> safe early exit
    const int r0 = chunk * 16;
    const int cg = l & 15, rg = l >> 4;
    const int c0 = cg * 8;
    float* xw = xs[wid];
    const float* xg = x + (size_t)r0 * DD;
    #pragma unroll
    for (int i = 0; i < 8; ++i) {       // stage 16 rows (2048 f32) into padded LDS
        int idx = (i * 64 + l) * 4;
        float4 v = *(const float4*)(xg + idx);
        int row = idx >> 7, col = idx & 127;
        *(float4*)(xw + row * 132 + col) = v;
    }
    float acc[4][8];
    #pragma unroll
    for (int rr = 0; rr < 4; ++rr)
        #pragma unroll
        for (int c = 0; c < 8; ++c) acc[rr][c] = 0.f;

    const float* wp = Wt + c0;
    const float* xr = xw + rg * 4 * 132;
    #pragma unroll 2
    for (int k = 0; k < DD; k += 4) {
        float4 xv[4];
        #pragma unroll
        for (int rr = 0; rr < 4; ++rr) xv[rr] = *(const float4*)(xr + rr * 132 + k);
        #pragma unroll
        for (int kk = 0; kk < 4; ++kk) {
            float4 w0 = *(const float4*)(wp + (k + kk) * DD);
            float4 w1 = *(const float4*)(wp + (k + kk) * DD + 4);
            float wv[8] = {w0.x, w0.y, w0.z, w0.w, w1.x, w1.y, w1.z, w1.w};
            #pragma unroll
            for (int rr = 0; rr < 4; ++rr) {
                float xk = (kk == 0) ? xv[rr].x : (kk == 1) ? xv[rr].y
                         : (kk == 2) ? xv[rr].z : xv[rr].w;
                #pragma unroll
                for (int c = 0; c < 8; ++c) acc[rr][c] = fmaf(xk, wv[c], acc[rr][c]);
            }
        }
    }
    float as_[8], ad_[8];
    #pragma unroll
    for (int c = 0; c < 8; ++c) { as_[c] = a[c0 + c]; ad_[c] = a[DD + c0 + c]; }
    #pragma unroll
    for (int rr = 0; rr < 4; ++rr) {
        float ps = 0.f, pd = 0.f;
        #pragma unroll
        for (int c = 0; c < 8; ++c) {
            ps = fmaf(acc[rr][c], as_[c], ps);
            pd = fmaf(acc[rr][c], ad_[c], pd);
        }
        #pragma unroll
        for (int o = 8; o > 0; o >>= 1) {   // reduce over the 16 col-group lanes
            ps += __shfl_xor(ps, o);
            pd += __shfl_xor(pd, o);
        }
        int row = r0 + rg * 4 + rr;
        if (cg == 0) { sArr[row] = ps; dArr[row] = pd; }
        *(float4*)(h + (size_t)row * DD + c0)     = make_float4(acc[rr][0], acc[rr][1], acc[rr][2], acc[rr][3]);
        *(float4*)(h + (size_t)row * DD + c0 + 4) = make_float4(acc[rr][4], acc[rr][5], acc[rr][6], acc[rr][7]);
    }
}

// ---------- histogram of dst ----------
__global__ __launch_bounds__(256) void hist_k(const int* __restrict__ dst, int* __restrict__ cnt) {
    int i = blockIdx.x * 256 + threadIdx.x;
    if (i < NE) atomicAdd(&cnt[dst[i]], 1);
}

// ---------- scan stage A: per-256-chunk sums ----------
__global__ __launch_bounds__(256) void scan_a_k(const int* __restrict__ cnt, int* __restrict__ csum) {
    __shared__ int red[4];
    int b = blockIdx.x, t = threadIdx.x;
    int i = b * 256 + t;
    int v = (i < NN) ? cnt[i] : 0;
    #pragma unroll
    for (int o = 32; o > 0; o >>= 1) v += __shfl_down(v, o);
    if ((t & 63) == 0) red[t >> 6] = v;
    __syncthreads();
    if (t == 0) csum[b] = red[0] + red[1] + red[2] + red[3];
}

// ---------- scan stage B: scan chunk sums (tiny) ----------
__global__ __launch_bounds__(256) void scan_b_k(const int* __restrict__ csum,
                                                int* __restrict__ base, int* __restrict__ off) {
    __shared__ int sh[NB_SCAN];
    int t = threadIdx.x;
    if (t < NB_SCAN) sh[t] = csum[t];
    __syncthreads();
    if (t == 0) {
        int run = 0;
        for (int b = 0; b < NB_SCAN; ++b) { int c = sh[b]; sh[b] = run; run += c; }
        off[NN] = run;
    }
    __syncthreads();
    if (t < NB_SCAN) base[t] = sh[t];
}

// ---------- scan stage C: exclusive offsets per node ----------
__global__ __launch_bounds__(256) void scan_c_k(const int* __restrict__ cnt,
                                                const int* __restrict__ base, int* __restrict__ off) {
    __shared__ int sh[256];
    int b = blockIdx.x, t = threadIdx.x, i = b * 256 + t;
    sh[t] = (i < NN) ? cnt[i] : 0;
    __syncthreads();
    if (t == 0) {
        int run = base[b];
        for (int j = 0; j < 256; ++j) { int c = sh[j]; sh[j] = run; run += c; }
    }
    __syncthreads();
    if (i < NN) off[i] = sh[t];
}

// ---------- scatter edges into CSR records (src, e) ----------
__global__ __launch_bounds__(256) void scatter_k(const int* __restrict__ src, const int* __restrict__ dst,
                                                 const float* __restrict__ sArr, const float* __restrict__ dArr,
                                                 const int* __restrict__ off, int* __restrict__ cur,
                                                 int2* __restrict__ rec) {
    int i = blockIdx.x * 256 + threadIdx.x;
    if (i >= NE) return;
    int sv = src[i], dv = dst[i];
    float z = sArr[sv] + dArr[dv];
    float e = 1.0f / (1.0f + __expf(-z));
    int p = atomicAdd(&cur[dv], 1);
    int2 r; r.x = sv; r.y = __float_as_int(e);
    rec[off[dv] + p] = r;
}

// ---------- aggregate: one wave per destination node, atomic-free ----------
__global__ __launch_bounds__(256) void agg_k(const float* __restrict__ h, const int* __restrict__ off,
                                             const int2* __restrict__ rec, float* __restrict__ out) {
    int wid = threadIdx.x >> 6, l = threadIdx.x & 63;
    int n = blockIdx.x * 4 + wid;
    if (n >= NN) return;
    int beg = off[n], end = off[n + 1];
    const float2* hp = (const float2*)h;
    float2 acc0 = make_float2(0.f, 0.f), acc1 = make_float2(0.f, 0.f);
    int j = beg;
    for (; j + 1 < end; j += 2) {
        int2 r0 = rec[j], r1 = rec[j + 1];
        float e0 = __int_as_float(r0.y), e1 = __int_as_float(r1.y);
        float2 h0 = hp[(size_t)r0.x * 64 + l];
        float2 h1 = hp[(size_t)r1.x * 64 + l];
        acc0.x = fmaf(e0, h0.x, acc0.x); acc0.y = fmaf(e0, h0.y, acc0.y);
        acc1.x = fmaf(e1, h1.x, acc1.x); acc1.y = fmaf(e1, h1.y, acc1.y);
    }
    if (j < end) {
        int2 r0 = rec[j];
        float e0 = __int_as_float(r0.y);
        float2 h0 = hp[(size_t)r0.x * 64 + l];
        acc0.x = fmaf(e0, h0.x, acc0.x); acc0.y = fmaf(e0, h0.y, acc0.y);
    }
    float2 res = make_float2(acc0.x + acc1.x, acc0.y + acc1.y);
    ((float2*)out)[(size_t)n * 64 + l] = res;
}

// ---------- fallback: direct atomic scatter-add (if ws too small for CSR) ----------
__global__ __launch_bounds__(256) void edge_atomic_k(const int* __restrict__ src, const int* __restrict__ dst,
                                                     const float* __restrict__ sArr, const float* __restrict__ dArr,
                                                     const float* __restrict__ h, float* __restrict__ out) {
    int wid = threadIdx.x >> 6, l = threadIdx.x & 63;
    int e = blockIdx.x * 4 + wid;
    if (e >= NE) return;
    int sv = src[e], dv = dst[e];
    float z = sArr[sv] + dArr[dv];
    float ev = 1.0f / (1.0f + __expf(-z));
    float2 hv = ((const float2*)h)[(size_t)sv * 64 + l];
    atomicAdd(&out[(size_t)dv * DD + 2 * l],     ev * hv.x);
    atomicAdd(&out[(size_t)dv * DD + 2 * l + 1], ev * hv.y);
}

extern "C" void kernel_launch(void* const* d_in, const int* in_sizes, int n_in,
                              void* d_out, int out_size, void* d_ws, size_t ws_size,
                              hipStream_t stream) {
    const float* x  = (const float*)d_in[0];
    const float* W  = (const float*)d_in[1];
    const float* a  = (const float*)d_in[2];
    const int* src  = (const int*)d_in[3];
    const int* dst  = (const int*)d_in[4];
    float* out = (float*)d_out;

    float* h    = (float*)d_ws;          // NN*DD
    float* Wt   = h + (size_t)NN * DD;   // DD*DD
    float* sA   = Wt + DD * DD;          // NN
    float* dA   = sA + NN;               // NN
    int*   cnt  = (int*)(dA + NN);       // NN
    int*   cur  = cnt + NN;              // NN
    int*   off  = cur + NN;              // NN+1
    int*   csum = off + NN + 4;          // NB_SCAN
    int*   base = csum + NB_SCAN;        // NB_SCAN
    int2*  rec  = (int2*)(((uintptr_t)(base + NB_SCAN) + 15) & ~(uintptr_t)15);
    size_t need = (size_t)((char*)(rec + NE) - (char*)d_ws);

    if (ws_size >= need) {
        hipMemsetAsync(cnt, 0, sizeof(int) * 2 * NN, stream);          // cnt + cur
        transpose_w_k<<<64, 256, 0, stream>>>(W, Wt);
        gemm_h_k<<<(NCHUNK + 3) / 4, 256, 0, stream>>>(x, Wt, a, h, sA, dA);
        hist_k<<<NE / 256, 256, 0, stream>>>(dst, cnt);
        scan_a_k<<<NB_SCAN, 256, 0, stream>>>(cnt, csum);
        scan_b_k<<<1, 256, 0, stream>>>(csum, base, off);
        scan_c_k<<<NB_SCAN, 256, 0, stream>>>(cnt, base, off);
        scatter_k<<<NE / 256, 256, 0, stream>>>(src, dst, sA, dA, off, cur, rec);
        agg_k<<<NN / 4, 256, 0, stream>>>(h, off, rec, out);
    } else {
        // minimal-footprint fallback: h + small arrays, atomics into out
        hipMemsetAsync(out, 0, sizeof(float) * (size_t)NN * DD, stream);
        transpose_w_k<<<64, 256, 0, stream>>>(W, Wt);
        gemm_h_k<<<(NCHUNK + 3) / 4, 256, 0, stream>>>(x, Wt, a, h, sA, dA);
        edge_atomic_k<<<NE / 4, 256, 0, stream>>>(src, dst, sA, dA, h, out);
    }
}

// Round 2
// 184.713 us; speedup vs baseline: 1.0792x; 1.0792x over previous
//
#include <hip/hip_runtime.h>
#include <hip/hip_bf16.h>
#include <stdint.h>

#define NN 50000
#define NE 800000
#define DD 128
#define NCHUNK 3125      // NN/16
#define NB_SCAN 196      // ceil(NN/256)

typedef __attribute__((ext_vector_type(8))) unsigned short ushort8;

__device__ inline uint16_t f2bf(float f) {            // round-to-nearest-even f32->bf16
    uint32_t u = __float_as_uint(f);
    return (uint16_t)((u + 0x7fffu + ((u >> 16) & 1u)) >> 16);
}
__device__ inline float bf_lo(uint32_t u) { return __uint_as_float(u << 16); }
__device__ inline float bf_hi(uint32_t u) { return __uint_as_float(u & 0xffff0000u); }

// ---------- W transpose: Wt[k][j] = W[j][k] ----------
__global__ __launch_bounds__(256) void transpose_w_k(const float* __restrict__ W,
                                                     float* __restrict__ Wt) {
    int i = blockIdx.x * 256 + threadIdx.x;
    if (i < DD * DD) {
        int j = i >> 7, k = i & 127;
        Wt[k * DD + j] = W[i];
    }
}

// ---------- GEMM: h = x @ W^T (f32 compute, bf16 store), s/d projections f32 ----------
__global__ __launch_bounds__(256) void gemm_h_k(const float* __restrict__ x,
                                                const float* __restrict__ Wt,
                                                const float* __restrict__ a,
                                                uint16_t* __restrict__ hb,
                                                float* __restrict__ sArr,
                                                float* __restrict__ dArr) {
    __shared__ float xs[4][16 * 132];
    const int tid = threadIdx.x;
    const int wid = tid >> 6;
    const int l   = tid & 63;
    const int chunk = blockIdx.x * 4 + wid;
    if (chunk >= NCHUNK) return;
    const int r0 = chunk * 16;
    const int cg = l & 15, rg = l >> 4;
    const int c0 = cg * 8;
    float* xw = xs[wid];
    const float* xg = x + (size_t)r0 * DD;
    #pragma unroll
    for (int i = 0; i < 8; ++i) {
        int idx = (i * 64 + l) * 4;
        float4 v = *(const float4*)(xg + idx);
        int row = idx >> 7, col = idx & 127;
        *(float4*)(xw + row * 132 + col) = v;
    }
    float acc[4][8];
    #pragma unroll
    for (int rr = 0; rr < 4; ++rr)
        #pragma unroll
        for (int c = 0; c < 8; ++c) acc[rr][c] = 0.f;

    const float* wp = Wt + c0;
    const float* xr = xw + rg * 4 * 132;
    #pragma unroll 2
    for (int k = 0; k < DD; k += 4) {
        float4 xv[4];
        #pragma unroll
        for (int rr = 0; rr < 4; ++rr) xv[rr] = *(const float4*)(xr + rr * 132 + k);
        #pragma unroll
        for (int kk = 0; kk < 4; ++kk) {
            float4 w0 = *(const float4*)(wp + (k + kk) * DD);
            float4 w1 = *(const float4*)(wp + (k + kk) * DD + 4);
            float wv[8] = {w0.x, w0.y, w0.z, w0.w, w1.x, w1.y, w1.z, w1.w};
            #pragma unroll
            for (int rr = 0; rr < 4; ++rr) {
                float xk = (kk == 0) ? xv[rr].x : (kk == 1) ? xv[rr].y
                         : (kk == 2) ? xv[rr].z : xv[rr].w;
                #pragma unroll
                for (int c = 0; c < 8; ++c) acc[rr][c] = fmaf(xk, wv[c], acc[rr][c]);
            }
        }
    }
    float as_[8], ad_[8];
    #pragma unroll
    for (int c = 0; c < 8; ++c) { as_[c] = a[c0 + c]; ad_[c] = a[DD + c0 + c]; }
    #pragma unroll
    for (int rr = 0; rr < 4; ++rr) {
        float ps = 0.f, pd = 0.f;
        #pragma unroll
        for (int c = 0; c < 8; ++c) {
            ps = fmaf(acc[rr][c], as_[c], ps);
            pd = fmaf(acc[rr][c], ad_[c], pd);
        }
        #pragma unroll
        for (int o = 8; o > 0; o >>= 1) {
            ps += __shfl_xor(ps, o);
            pd += __shfl_xor(pd, o);
        }
        int row = r0 + rg * 4 + rr;
        if (cg == 0) { sArr[row] = ps; dArr[row] = pd; }
        ushort8 hv;
        #pragma unroll
        for (int c = 0; c < 8; ++c) hv[c] = f2bf(acc[rr][c]);
        *(ushort8*)(hb + (size_t)row * DD + c0) = hv;
    }
}

// ---------- histogram of dst ----------
__global__ __launch_bounds__(256) void hist_k(const int* __restrict__ dst, int* __restrict__ cnt) {
    int i = blockIdx.x * 256 + threadIdx.x;
    if (i < NE) atomicAdd(&cnt[dst[i]], 1);
}

// ---------- scan stage A ----------
__global__ __launch_bounds__(256) void scan_a_k(const int* __restrict__ cnt, int* __restrict__ csum) {
    __shared__ int red[4];
    int b = blockIdx.x, t = threadIdx.x;
    int i = b * 256 + t;
    int v = (i < NN) ? cnt[i] : 0;
    #pragma unroll
    for (int o = 32; o > 0; o >>= 1) v += __shfl_down(v, o);
    if ((t & 63) == 0) red[t >> 6] = v;
    __syncthreads();
    if (t == 0) csum[b] = red[0] + red[1] + red[2] + red[3];
}

// ---------- scan stage B ----------
__global__ __launch_bounds__(256) void scan_b_k(const int* __restrict__ csum,
                                                int* __restrict__ base, int* __restrict__ off) {
    __shared__ int sh[NB_SCAN];
    int t = threadIdx.x;
    if (t < NB_SCAN) sh[t] = csum[t];
    __syncthreads();
    if (t == 0) {
        int run = 0;
        for (int b = 0; b < NB_SCAN; ++b) { int c = sh[b]; sh[b] = run; run += c; }
        off[NN] = run;
    }
    __syncthreads();
    if (t < NB_SCAN) base[t] = sh[t];
}

// ---------- scan stage C: off[i] and cur[i]=off[i] ----------
__global__ __launch_bounds__(256) void scan_c_k(const int* __restrict__ cnt,
                                                const int* __restrict__ base,
                                                int* __restrict__ off, int* __restrict__ cur) {
    __shared__ int sh[256];
    int b = blockIdx.x, t = threadIdx.x, i = b * 256 + t;
    sh[t] = (i < NN) ? cnt[i] : 0;
    __syncthreads();
    if (t == 0) {
        int run = base[b];
        for (int j = 0; j < 256; ++j) { int c = sh[j]; sh[j] = run; run += c; }
    }
    __syncthreads();
    if (i < NN) { off[i] = sh[t]; cur[i] = sh[t]; }
}

// ---------- scatter: rec[slot] = src (4B records) ----------
__global__ __launch_bounds__(256) void scatter_k(const int* __restrict__ src, const int* __restrict__ dst,
                                                 int* __restrict__ cur, int* __restrict__ rec) {
    int i = blockIdx.x * 256 + threadIdx.x;
    if (i >= NE) return;
    int dv = dst[i];
    int p = atomicAdd(&cur[dv], 1);
    rec[p] = src[i];
}

// ---------- aggregate: one wave per node, 4-deep ILP, bf16 h ----------
__global__ __launch_bounds__(256) void agg_k(const uint32_t* __restrict__ hb,
                                             const float* __restrict__ sArr,
                                             const float* __restrict__ dArr,
                                             const int* __restrict__ off,
                                             const int* __restrict__ rec,
                                             float* __restrict__ out) {
    int wid = threadIdx.x >> 6, l = threadIdx.x & 63;
    int n = blockIdx.x * 4 + wid;
    if (n >= NN) return;
    int beg = off[n], end = off[n + 1];
    float dn = dArr[n];
    float2 a0 = {0.f, 0.f}, a1 = {0.f, 0.f}, a2 = {0.f, 0.f}, a3 = {0.f, 0.f};
    int j = beg;
    for (; j + 3 < end; j += 4) {
        int s0 = rec[j], s1 = rec[j + 1], s2 = rec[j + 2], s3 = rec[j + 3];
        uint32_t u0 = hb[(size_t)s0 * 64 + l];
        uint32_t u1 = hb[(size_t)s1 * 64 + l];
        uint32_t u2 = hb[(size_t)s2 * 64 + l];
        uint32_t u3 = hb[(size_t)s3 * 64 + l];
        float z0 = sArr[s0] + dn, z1 = sArr[s1] + dn;
        float z2 = sArr[s2] + dn, z3 = sArr[s3] + dn;
        float e0 = 1.f / (1.f + __expf(-z0));
        float e1 = 1.f / (1.f + __expf(-z1));
        float e2 = 1.f / (1.f + __expf(-z2));
        float e3 = 1.f / (1.f + __expf(-z3));
        a0.x = fmaf(e0, bf_lo(u0), a0.x); a0.y = fmaf(e0, bf_hi(u0), a0.y);
        a1.x = fmaf(e1, bf_lo(u1), a1.x); a1.y = fmaf(e1, bf_hi(u1), a1.y);
        a2.x = fmaf(e2, bf_lo(u2), a2.x); a2.y = fmaf(e2, bf_hi(u2), a2.y);
        a3.x = fmaf(e3, bf_lo(u3), a3.x); a3.y = fmaf(e3, bf_hi(u3), a3.y);
    }
    for (; j < end; ++j) {
        int s0 = rec[j];
        uint32_t u0 = hb[(size_t)s0 * 64 + l];
        float z0 = sArr[s0] + dn;
        float e0 = 1.f / (1.f + __expf(-z0));
        a0.x = fmaf(e0, bf_lo(u0), a0.x); a0.y = fmaf(e0, bf_hi(u0), a0.y);
    }
    float2 res;
    res.x = (a0.x + a1.x) + (a2.x + a3.x);
    res.y = (a0.y + a1.y) + (a2.y + a3.y);
    ((float2*)out)[(size_t)n * 64 + l] = res;
}

// ---------- fallback: direct atomic scatter-add ----------
__global__ __launch_bounds__(256) void edge_atomic_k(const int* __restrict__ src, const int* __restrict__ dst,
                                                     const float* __restrict__ sArr, const float* __restrict__ dArr,
                                                     const uint32_t* __restrict__ hb, float* __restrict__ out) {
    int wid = threadIdx.x >> 6, l = threadIdx.x & 63;
    int e = blockIdx.x * 4 + wid;
    if (e >= NE) return;
    int sv = src[e], dv = dst[e];
    float z = sArr[sv] + dArr[dv];
    float ev = 1.0f / (1.0f + __expf(-z));
    uint32_t u = hb[(size_t)sv * 64 + l];
    atomicAdd(&out[(size_t)dv * DD + 2 * l],     ev * bf_lo(u));
    atomicAdd(&out[(size_t)dv * DD + 2 * l + 1], ev * bf_hi(u));
}

extern "C" void kernel_launch(void* const* d_in, const int* in_sizes, int n_in,
                              void* d_out, int out_size, void* d_ws, size_t ws_size,
                              hipStream_t stream) {
    const float* x  = (const float*)d_in[0];
    const float* W  = (const float*)d_in[1];
    const float* a  = (const float*)d_in[2];
    const int* src  = (const int*)d_in[3];
    const int* dst  = (const int*)d_in[4];
    float* out = (float*)d_out;

    char* p = (char*)d_ws;
    uint16_t* hb = (uint16_t*)p;            p += (size_t)NN * DD * 2;   // 12.8 MB
    float* Wt    = (float*)p;               p += (size_t)DD * DD * 4;
    float* sA    = (float*)p;               p += (size_t)NN * 4;
    float* dA    = (float*)p;               p += (size_t)NN * 4;
    int*   cnt   = (int*)p;                 p += (size_t)NN * 4;
    int*   cur   = (int*)p;                 p += (size_t)NN * 4;
    int*   off   = (int*)p;                 p += (size_t)(NN + 4) * 4;
    int*   csum  = (int*)p;                 p += (size_t)NB_SCAN * 4;
    int*   base  = (int*)p;                 p += (size_t)NB_SCAN * 4;
    int*   rec   = (int*)p;                 p += (size_t)NE * 4;        // 3.2 MB
    size_t need  = (size_t)(p - (char*)d_ws);

    if (ws_size >= need) {
        hipMemsetAsync(cnt, 0, sizeof(int) * NN, stream);
        transpose_w_k<<<64, 256, 0, stream>>>(W, Wt);
        gemm_h_k<<<(NCHUNK + 3) / 4, 256, 0, stream>>>(x, Wt, a, hb, sA, dA);
        hist_k<<<NE / 256, 256, 0, stream>>>(dst, cnt);
        scan_a_k<<<NB_SCAN, 256, 0, stream>>>(cnt, csum);
        scan_b_k<<<1, 256, 0, stream>>>(csum, base, off);
        scan_c_k<<<NB_SCAN, 256, 0, stream>>>(cnt, base, off, cur);
        scatter_k<<<NE / 256, 256, 0, stream>>>(src, dst, cur, rec);
        agg_k<<<NN / 4, 256, 0, stream>>>((const uint32_t*)hb, sA, dA, off, rec, out);
    } else {
        hipMemsetAsync(out, 0, sizeof(float) * (size_t)NN * DD, stream);
        transpose_w_k<<<64, 256, 0, stream>>>(W, Wt);
        gemm_h_k<<<(NCHUNK + 3) / 4, 256, 0, stream>>>(x, Wt, a, hb, sA, dA);
        edge_atomic_k<<<NE / 4, 256, 0, stream>>>(src, dst, sA, dA, (const uint32_t*)hb, out);
    }
}